// Round 4
// baseline (326.947 us; speedup 1.0000x reference)
//
#include <hip/hip_runtime.h>
#include <math.h>

#define NFEAT 1024
#define NROWS 32768
#define EPS 1e-5f

#define NB1 1024                       // reduce blocks: 4/CU x 256 CUs
#define RPB1 (NROWS / NB1)             // 32 rows per reduce block
#define FG (NFEAT / 4)                 // 256 float4 col-groups per row
#define NB3 2048                       // norm blocks
#define RPB3 (NROWS / NB3)             // 16 rows per norm block

// native vector type: accepted by __builtin_nontemporal_store (HIP float4 is not)
typedef float f32x4 __attribute__((ext_vector_type(4)));

// ws layout (floats):
//   [0    .. 1023]  sums    (atomic target, zeroed by 8KB memset each launch)
//   [1024 .. 2047]  sumsq
// No partial buffers anymore: stage-1 blocks atomicAdd straight into stats.

__global__ __launch_bounds__(256) void reduce_kernel(
    const float* __restrict__ x,
    float* __restrict__ sums, float* __restrict__ sumsq)
{
    const int t = threadIdx.x;                 // col-group 0..255
    const size_t base = (size_t)(blockIdx.x * RPB1) * FG + t;
    const f32x4* xv = (const f32x4*)x;

    f32x4 s = {0.f, 0.f, 0.f, 0.f};
    f32x4 q = {0.f, 0.f, 0.f, 0.f};

    #pragma unroll
    for (int r = 0; r < RPB1; r += 4) {
        // 4 independent loads in flight per wave
        f32x4 v0 = xv[base + (size_t)(r + 0) * FG];
        f32x4 v1 = xv[base + (size_t)(r + 1) * FG];
        f32x4 v2 = xv[base + (size_t)(r + 2) * FG];
        f32x4 v3 = xv[base + (size_t)(r + 3) * FG];
        s += v0 + v1 + v2 + v3;                       // fp-contract fuses to fma
        q += v0 * v0 + v1 * v1 + v2 * v2 + v3 * v3;
    }

    // 8 device-scope float atomics per thread; 1024 contributions per address,
    // pipelined at L2 and overlapped with other blocks' loads.
    const int c = 4 * t;
    atomicAdd(&sums[c + 0], s.x);  atomicAdd(&sums[c + 1], s.y);
    atomicAdd(&sums[c + 2], s.z);  atomicAdd(&sums[c + 3], s.w);
    atomicAdd(&sumsq[c + 0], q.x); atomicAdd(&sumsq[c + 1], q.y);
    atomicAdd(&sumsq[c + 2], q.z); atomicAdd(&sumsq[c + 3], q.w);
}

__global__ __launch_bounds__(256) void norm_kernel(
    const float* __restrict__ x,
    const float* __restrict__ sums, const float* __restrict__ sumsq,
    float* __restrict__ out)
{
    const int t = threadIdx.x;
    const size_t base = (size_t)(blockIdx.x * RPB3) * FG + t;
    const f32x4* xv = (const f32x4*)x;
    f32x4* ov = (f32x4*)out;

    // finalize stats per thread (8 KB stays L2-hot; ~20 ALU ops, free)
    f32x4 S = ((const f32x4*)sums)[t];
    f32x4 Q = ((const f32x4*)sumsq)[t];
    const float n   = (float)NROWS;
    const float rn  = 1.0f / n;
    const float rn1 = 1.0f / (n - 1.0f);
    f32x4 m, iv;
    m = S * rn;
    iv.x = 1.0f / (sqrtf((Q.x - S.x * S.x * rn) * rn1) + EPS);
    iv.y = 1.0f / (sqrtf((Q.y - S.y * S.y * rn) * rn1) + EPS);
    iv.z = 1.0f / (sqrtf((Q.z - S.z * S.z * rn) * rn1) + EPS);
    iv.w = 1.0f / (sqrtf((Q.w - S.w * S.w * rn) * rn1) + EPS);

    #pragma unroll
    for (int r = 0; r < RPB3; r += 4) {
        f32x4 v0 = xv[base + (size_t)(r + 0) * FG];
        f32x4 v1 = xv[base + (size_t)(r + 1) * FG];
        f32x4 v2 = xv[base + (size_t)(r + 2) * FG];
        f32x4 v3 = xv[base + (size_t)(r + 3) * FG];
        f32x4 o0 = (v0 - m) * iv;
        f32x4 o1 = (v1 - m) * iv;
        f32x4 o2 = (v2 - m) * iv;
        f32x4 o3 = (v3 - m) * iv;
        // nontemporal: out never re-read; keep x resident in L3 for this pass
        __builtin_nontemporal_store(o0, &ov[base + (size_t)(r + 0) * FG]);
        __builtin_nontemporal_store(o1, &ov[base + (size_t)(r + 1) * FG]);
        __builtin_nontemporal_store(o2, &ov[base + (size_t)(r + 2) * FG]);
        __builtin_nontemporal_store(o3, &ov[base + (size_t)(r + 3) * FG]);
    }
}

extern "C" void kernel_launch(void* const* d_in, const int* in_sizes, int n_in,
                              void* d_out, int out_size, void* d_ws, size_t ws_size,
                              hipStream_t stream) {
    const float* x = (const float*)d_in[0];
    float* out = (float*)d_out;

    float* sums  = (float*)d_ws;                 // [1024]
    float* sumsq = sums + NFEAT;                 // [1024]

    hipMemsetAsync(d_ws, 0, 2 * NFEAT * sizeof(float), stream);  // zero stats
    reduce_kernel<<<NB1, 256, 0, stream>>>(x, sums, sumsq);
    norm_kernel<<<NB3, 256, 0, stream>>>(x, sums, sumsq, out);
}

// Round 5
// 276.565 us; speedup vs baseline: 1.1822x; 1.1822x over previous
//
#include <hip/hip_runtime.h>
#include <math.h>

#define NFEAT 1024
#define NROWS 32768
#define EPS 1e-5f

#define NB1 2048                       // stage-1 blocks: 8/CU x 256 CUs
#define RPB1 (NROWS / NB1)             // 16 rows per stage-1 block
#define FG (NFEAT / 4)                 // 256 float4 col-groups per row
#define NB2 FG                         // stage-2: one block per col-group
#define NB3 2048                       // norm blocks
#define RPB3 (NROWS / NB3)             // 16 rows per norm block

// native vector type: accepted by __builtin_nontemporal_store (HIP float4 is not)
typedef float f32x4 __attribute__((ext_vector_type(4)));

// ws layout (floats):
//   [0      .. 1023 ]  mean        (written by reduce2, read by norm)
//   [1024   .. 2047 ]  inv_std
//   [2048   .. ]       partial_s: NB1*FG float4s (8 MB), then partial_q (8 MB)
// Nothing read before written this launch -> no memset.

// 8 blocks/CU (launch_bounds min-waves 8 with 256-thread blocks) -> VGPR<=64,
// 8 waves/SIMD. 8 float4 loads in flight per thread -> 64KB in flight per SIMD.
__global__ __launch_bounds__(256, 8) void reduce1_kernel(
    const float* __restrict__ x, f32x4* __restrict__ ps, f32x4* __restrict__ pq)
{
    const int t = threadIdx.x;                 // col-group 0..255
    const size_t base = (size_t)(blockIdx.x * RPB1) * FG + t;
    const f32x4* xv = (const f32x4*)x;

    f32x4 s = {0.f, 0.f, 0.f, 0.f};
    f32x4 q = {0.f, 0.f, 0.f, 0.f};

    #pragma unroll
    for (int rr = 0; rr < RPB1; rr += 8) {
        // 8 independent loads in flight
        f32x4 v0 = xv[base + (size_t)(rr + 0) * FG];
        f32x4 v1 = xv[base + (size_t)(rr + 1) * FG];
        f32x4 v2 = xv[base + (size_t)(rr + 2) * FG];
        f32x4 v3 = xv[base + (size_t)(rr + 3) * FG];
        f32x4 v4 = xv[base + (size_t)(rr + 4) * FG];
        f32x4 v5 = xv[base + (size_t)(rr + 5) * FG];
        f32x4 v6 = xv[base + (size_t)(rr + 6) * FG];
        f32x4 v7 = xv[base + (size_t)(rr + 7) * FG];
        s += ((v0 + v1) + (v2 + v3)) + ((v4 + v5) + (v6 + v7));
        q += ((v0 * v0 + v1 * v1) + (v2 * v2 + v3 * v3))
           + ((v4 * v4 + v5 * v5) + (v6 * v6 + v7 * v7));
    }
    ps[(size_t)blockIdx.x * FG + t] = s;       // no atomics
    pq[(size_t)blockIdx.x * FG + t] = q;
}

// 256 blocks (one col-group each) x 256 threads: full-grid, deterministic,
// no atomics; finalizes mean / 1/(std+eps). Partials are L2-hot.
__global__ __launch_bounds__(256) void reduce2_kernel(
    const f32x4* __restrict__ ps, const f32x4* __restrict__ pq,
    f32x4* __restrict__ mean, f32x4* __restrict__ inv)
{
    const int t = threadIdx.x;
    const int cgi = blockIdx.x;                // col-group 0..255

    f32x4 s = {0.f, 0.f, 0.f, 0.f};
    f32x4 q = {0.f, 0.f, 0.f, 0.f};
    #pragma unroll
    for (int k = 0; k < NB1 / 256; ++k) {      // 8 partial-rows per thread
        s += ps[(size_t)(t + 256 * k) * FG + cgi];
        q += pq[(size_t)(t + 256 * k) * FG + cgi];
    }

    __shared__ f32x4 ls[256];
    __shared__ f32x4 lq[256];
    ls[t] = s; lq[t] = q;
    __syncthreads();
    #pragma unroll
    for (int off = 128; off > 0; off >>= 1) {
        if (t < off) {
            ls[t] += ls[t + off];
            lq[t] += lq[t + off];
        }
        __syncthreads();
    }

    if (t == 0) {
        f32x4 S = ls[0], Q = lq[0];
        const float n   = (float)NROWS;
        const float rn  = 1.0f / n;
        const float rn1 = 1.0f / (n - 1.0f);
        f32x4 m = S * rn, iv;
        iv.x = 1.0f / (sqrtf((Q.x - S.x * S.x * rn) * rn1) + EPS);
        iv.y = 1.0f / (sqrtf((Q.y - S.y * S.y * rn) * rn1) + EPS);
        iv.z = 1.0f / (sqrtf((Q.z - S.z * S.z * rn) * rn1) + EPS);
        iv.w = 1.0f / (sqrtf((Q.w - S.w * S.w * rn) * rn1) + EPS);
        mean[cgi] = m;
        inv[cgi]  = iv;
    }
}

__global__ __launch_bounds__(256) void norm_kernel(
    const float* __restrict__ x,
    const f32x4* __restrict__ mean, const f32x4* __restrict__ inv,
    float* __restrict__ out)
{
    const int t = threadIdx.x;
    const size_t base = (size_t)(blockIdx.x * RPB3) * FG + t;
    const f32x4* xv = (const f32x4*)x;
    f32x4* ov = (f32x4*)out;

    const f32x4 m  = mean[t];
    const f32x4 iv = inv[t];

    #pragma unroll
    for (int r = 0; r < RPB3; r += 4) {
        f32x4 v0 = xv[base + (size_t)(r + 0) * FG];
        f32x4 v1 = xv[base + (size_t)(r + 1) * FG];
        f32x4 v2 = xv[base + (size_t)(r + 2) * FG];
        f32x4 v3 = xv[base + (size_t)(r + 3) * FG];
        f32x4 o0 = (v0 - m) * iv;
        f32x4 o1 = (v1 - m) * iv;
        f32x4 o2 = (v2 - m) * iv;
        f32x4 o3 = (v3 - m) * iv;
        // nontemporal: out never re-read; keep x resident in L3
        __builtin_nontemporal_store(o0, &ov[base + (size_t)(r + 0) * FG]);
        __builtin_nontemporal_store(o1, &ov[base + (size_t)(r + 1) * FG]);
        __builtin_nontemporal_store(o2, &ov[base + (size_t)(r + 2) * FG]);
        __builtin_nontemporal_store(o3, &ov[base + (size_t)(r + 3) * FG]);
    }
}

extern "C" void kernel_launch(void* const* d_in, const int* in_sizes, int n_in,
                              void* d_out, int out_size, void* d_ws, size_t ws_size,
                              hipStream_t stream) {
    const float* x = (const float*)d_in[0];
    float* out = (float*)d_out;

    f32x4* mean = (f32x4*)d_ws;                      // [256] float4
    f32x4* inv  = mean + FG;                         // [256] float4
    f32x4* ps   = inv + FG;                          // NB1*FG float4s (8 MB)
    f32x4* pq   = ps + (size_t)NB1 * FG;             // NB1*FG float4s (8 MB)

    reduce1_kernel<<<NB1, 256, 0, stream>>>(x, ps, pq);
    reduce2_kernel<<<NB2, 256, 0, stream>>>(ps, pq, mean, inv);
    norm_kernel<<<NB3, 256, 0, stream>>>(x, mean, inv, out);
}

// Round 6
// 266.823 us; speedup vs baseline: 1.2253x; 1.0365x over previous
//
#include <hip/hip_runtime.h>
#include <math.h>

#define NFEAT 1024
#define NROWS 32768
#define EPS 1e-5f

#define NB1 1024                       // stage-1 blocks: 4/CU x 256 CUs
#define RPB1 (NROWS / NB1)             // 32 rows per stage-1 block
#define FG (NFEAT / 4)                 // 256 float4 col-groups per row
#define NB2 FG                         // stage-2: one block per col-group
#define NB3 2048                       // norm blocks
#define RPB3 (NROWS / NB3)             // 16 rows per norm block

typedef float f32x4 __attribute__((ext_vector_type(4)));

// ws layout (floats):
//   [0      .. 1023 ]  mean        (written by reduce2, read by norm)
//   [1024   .. 2047 ]  inv_std
//   [2048   .. ]       partial_s: NB1*FG float4s (4 MB), then partial_q (4 MB)
// Nothing read before written this launch -> no memset.

__global__ __launch_bounds__(256) void reduce1_kernel(
    const float* __restrict__ x, f32x4* __restrict__ ps, f32x4* __restrict__ pq)
{
    const int t = threadIdx.x;                 // col-group 0..255
    const size_t base = (size_t)(blockIdx.x * RPB1) * FG + t;
    const f32x4* xv = (const f32x4*)x;

    f32x4 s = {0.f, 0.f, 0.f, 0.f};
    f32x4 q = {0.f, 0.f, 0.f, 0.f};

    #pragma unroll
    for (int r = 0; r < RPB1; r += 4) {
        // 4 independent loads in flight per wave
        f32x4 v0 = xv[base + (size_t)(r + 0) * FG];
        f32x4 v1 = xv[base + (size_t)(r + 1) * FG];
        f32x4 v2 = xv[base + (size_t)(r + 2) * FG];
        f32x4 v3 = xv[base + (size_t)(r + 3) * FG];
        s += (v0 + v1) + (v2 + v3);
        q += (v0 * v0 + v1 * v1) + (v2 * v2 + v3 * v3);
    }
    ps[(size_t)blockIdx.x * FG + t] = s;       // no atomics
    pq[(size_t)blockIdx.x * FG + t] = q;
}

// 256 blocks (one col-group each) x 256 threads: full-grid, deterministic,
// no atomics; finalizes mean / 1/(std+eps). Partials are L2/L3-hot.
__global__ __launch_bounds__(256) void reduce2_kernel(
    const f32x4* __restrict__ ps, const f32x4* __restrict__ pq,
    f32x4* __restrict__ mean, f32x4* __restrict__ inv)
{
    const int t = threadIdx.x;
    const int cgi = blockIdx.x;                // col-group 0..255

    f32x4 s = {0.f, 0.f, 0.f, 0.f};
    f32x4 q = {0.f, 0.f, 0.f, 0.f};
    #pragma unroll
    for (int k = 0; k < NB1 / 256; ++k) {      // 4 partial-rows per thread
        s += ps[(size_t)(t + 256 * k) * FG + cgi];
        q += pq[(size_t)(t + 256 * k) * FG + cgi];
    }

    __shared__ f32x4 ls[256];
    __shared__ f32x4 lq[256];
    ls[t] = s; lq[t] = q;
    __syncthreads();
    #pragma unroll
    for (int off = 128; off > 0; off >>= 1) {
        if (t < off) {
            ls[t] += ls[t + off];
            lq[t] += lq[t + off];
        }
        __syncthreads();
    }

    if (t == 0) {
        f32x4 S = ls[0], Q = lq[0];
        const float n   = (float)NROWS;
        const float rn  = 1.0f / n;
        const float rn1 = 1.0f / (n - 1.0f);
        f32x4 m = S * rn, iv;
        iv.x = 1.0f / (sqrtf((Q.x - S.x * S.x * rn) * rn1) + EPS);
        iv.y = 1.0f / (sqrtf((Q.y - S.y * S.y * rn) * rn1) + EPS);
        iv.z = 1.0f / (sqrtf((Q.z - S.z * S.z * rn) * rn1) + EPS);
        iv.w = 1.0f / (sqrtf((Q.w - S.w * S.w * rn) * rn1) + EPS);
        mean[cgi] = m;
        inv[cgi]  = iv;
    }
}

__global__ __launch_bounds__(256) void norm_kernel(
    const float* __restrict__ x,
    const f32x4* __restrict__ mean, const f32x4* __restrict__ inv,
    float* __restrict__ out)
{
    const int t = threadIdx.x;
    const size_t base = (size_t)(blockIdx.x * RPB3) * FG + t;
    const f32x4* xv = (const f32x4*)x;
    f32x4* ov = (f32x4*)out;

    const f32x4 m  = mean[t];
    const f32x4 iv = inv[t];

    #pragma unroll
    for (int r = 0; r < RPB3; r += 4) {
        f32x4 v0 = xv[base + (size_t)(r + 0) * FG];
        f32x4 v1 = xv[base + (size_t)(r + 1) * FG];
        f32x4 v2 = xv[base + (size_t)(r + 2) * FG];
        f32x4 v3 = xv[base + (size_t)(r + 3) * FG];
        // plain stores this round: A/B vs round-2's nontemporal (one variable)
        ov[base + (size_t)(r + 0) * FG] = (v0 - m) * iv;
        ov[base + (size_t)(r + 1) * FG] = (v1 - m) * iv;
        ov[base + (size_t)(r + 2) * FG] = (v2 - m) * iv;
        ov[base + (size_t)(r + 3) * FG] = (v3 - m) * iv;
    }
}

extern "C" void kernel_launch(void* const* d_in, const int* in_sizes, int n_in,
                              void* d_out, int out_size, void* d_ws, size_t ws_size,
                              hipStream_t stream) {
    const float* x = (const float*)d_in[0];
    float* out = (float*)d_out;

    f32x4* mean = (f32x4*)d_ws;                      // [256] float4
    f32x4* inv  = mean + FG;                         // [256] float4
    f32x4* ps   = inv + FG;                          // NB1*FG float4s (4 MB)
    f32x4* pq   = ps + (size_t)NB1 * FG;             // NB1*FG float4s (4 MB)

    reduce1_kernel<<<NB1, 256, 0, stream>>>(x, ps, pq);
    reduce2_kernel<<<NB2, 256, 0, stream>>>(ps, pq, mean, inv);
    norm_kernel<<<NB3, 256, 0, stream>>>(x, mean, inv, out);
}